// Round 8
// baseline (123.826 us; speedup 1.0000x reference)
//
#include <hip/hip_runtime.h>
#include <hip/hip_bf16.h>

typedef __attribute__((ext_vector_type(4))) float f32x4;
typedef __attribute__((ext_vector_type(16))) float f32x16;
typedef __attribute__((ext_vector_type(8))) short short8;
typedef __attribute__((ext_vector_type(4))) int i32x4;

#define S_LEN 4096
#define DM    1024
#define NH    16
#define DH    64
#define WIN   256

__device__ inline unsigned short f2b(float f) {
  unsigned int x = __float_as_uint(f);
  unsigned int r = (x + 0x7fffu + ((x >> 16) & 1u)) >> 16;
  return (unsigned short)r;
}

__device__ inline void gload_lds16(const void* g, void* l) {
  __builtin_amdgcn_global_load_lds(
      (const __attribute__((address_space(1))) void*)g,
      (__attribute__((address_space(3))) void*)l, 16, 0, 0);
}

// ---------------------------------------------------------------------------
// Convert X and the 4 weight matrices f32 -> bf16.
// ---------------------------------------------------------------------------
__global__ __launch_bounds__(256) void cvt_all(
    const float* __restrict__ x,
    const float* __restrict__ qw, const float* __restrict__ kw,
    const float* __restrict__ vw, const float* __restrict__ ow,
    unsigned short* __restrict__ Xb, unsigned short* __restrict__ Wb)
{
  const int y = blockIdx.y;
  const float* src;
  unsigned short* dst;
  int n8;
  if (y == 0) { src = x; dst = Xb; n8 = (S_LEN * DM) / 8; }
  else {
    src = (y == 1) ? qw : (y == 2) ? kw : (y == 3) ? vw : ow;
    dst = Wb + (size_t)(y - 1) * DM * DM;
    n8 = (DM * DM) / 8;
  }
  const int i = blockIdx.x * 256 + threadIdx.x;
  if (i >= n8) return;
  const float4* s4 = (const float4*)src + (size_t)i * 2;
  float4 a = s4[0], b = s4[1];
  short8 v;
  v[0] = f2b(a.x); v[1] = f2b(a.y); v[2] = f2b(a.z); v[3] = f2b(a.w);
  v[4] = f2b(b.x); v[5] = f2b(b.y); v[6] = f2b(b.z); v[7] = f2b(b.w);
  *(short8*)(dst + (size_t)i * 8) = v;
}

// ---------------------------------------------------------------------------
// Deep-pipelined GEMM (round-4/5 version, measured best: qkv 40.5us, 0 bank
// conflicts): BK=64, double-buffered LDS, counted vmcnt(8), swizzled layout
// (col bits 4-6 ^= row bits 0-2 via pre-swizzled global src), setprio.
// ---------------------------------------------------------------------------
#define PIPE_WAIT8  asm volatile("s_waitcnt vmcnt(8)" ::: "memory")
#define PIPE_WAIT0  asm volatile("s_waitcnt vmcnt(0)" ::: "memory")
#define PIPE_BAR    do { __builtin_amdgcn_s_barrier(); __builtin_amdgcn_sched_barrier(0); } while (0)
#define PIPE_ENDBAR do { __builtin_amdgcn_sched_barrier(0); __builtin_amdgcn_s_barrier(); \
                         __builtin_amdgcn_sched_barrier(0); } while (0)

template<int BM, int BN, int NWM, int NWN, bool F32OUT>
__global__ __launch_bounds__(NWM* NWN * 64, 1) void gemm_bt(
    const unsigned short* __restrict__ A,
    const unsigned short* __restrict__ Wb,
    const float* __restrict__ b0, const float* __restrict__ b1, const float* __restrict__ b2,
    unsigned short* __restrict__ Obf,
    float* __restrict__ Of)
{
  constexpr int THREADS = NWM * NWN * 64;
  constexpr int MR = BM / (NWM * 16);
  constexpr int NR = BN / (NWN * 16);
  constexpr int RSM = BM / NWM;
  constexpr int RSN = BN / NWN;
  constexpr int REG = BM * 64;
  static_assert(BM == BN, "");
  static_assert((BM * 64 * 2) / (THREADS * 16) == 4, "4 staging rounds");

  const int z = blockIdx.z;
  const unsigned short* Bmat = Wb + (size_t)z * DM * DM;
  const float* bias = (z == 0) ? b0 : (z == 1) ? b1 : b2;
  unsigned short* O = Obf + (size_t)z * S_LEN * DM;

  __shared__ __align__(16) unsigned short LDS[4 * REG];
  unsigned short* A0 = LDS;
  unsigned short* A1 = LDS + REG;
  unsigned short* B0 = LDS + 2 * REG;
  unsigned short* B1 = LDS + 3 * REG;

  const int t = threadIdx.x;
  const int lane = t & 63, w = t >> 6;
  const int wm = w / NWN, wn = w % NWN;
  const int lr = lane & 15, lg = lane >> 4;
  const int m0 = blockIdx.x * BM, n0 = blockIdx.y * BN;

  int srow[4], scol[4], sbase[4];
#pragma unroll
  for (int i = 0; i < 4; ++i) {
    const int bo = (i * THREADS + w * 64) * 16;
    const int o = bo + lane * 16;
    const int row = o >> 7, colb = o & 127;
    const int colp = colb ^ ((row & 3) << 4) ^ (((row >> 2) & 1) << 6);
    srow[i] = row; scol[i] = colp >> 1; sbase[i] = bo >> 1;
  }

#define STAGE(e0, lA, lB)                                                           \
  do {                                                                              \
    _Pragma("unroll") for (int i = 0; i < 4; ++i) {                                 \
      gload_lds16(A + (size_t)(m0 + srow[i]) * DM + (e0) + scol[i], (lA) + sbase[i]); \
      gload_lds16(Bmat + (size_t)(n0 + srow[i]) * DM + (e0) + scol[i], (lB) + sbase[i]); \
    }                                                                               \
  } while (0)

  f32x4 acc[MR][NR];
#pragma unroll
  for (int m = 0; m < MR; ++m)
#pragma unroll
    for (int n = 0; n < NR; ++n) acc[m][n] = (f32x4){0.f, 0.f, 0.f, 0.f};

  const int xor6l = ((lr >> 2) & 1) << 6;
  const int xor45 = (lg << 4) ^ ((lr & 3) << 4);

#define COMPUTE(sAp, sBp)                                                           \
  do {                                                                              \
    _Pragma("unroll") for (int kk = 0; kk < 2; ++kk) {                              \
      const int coff = ((kk << 6) ^ xor6l) + xor45;                                 \
      short8 af[MR], bf[NR];                                                        \
      _Pragma("unroll") for (int m = 0; m < MR; ++m)                                \
        af[m] = *(const short8*)((const char*)(sAp) + (wm * RSM + m * 16 + lr) * 128 + coff); \
      _Pragma("unroll") for (int n = 0; n < NR; ++n)                                \
        bf[n] = *(const short8*)((const char*)(sBp) + (wn * RSN + n * 16 + lr) * 128 + coff); \
      _Pragma("unroll") for (int m = 0; m < MR; ++m)                                \
        _Pragma("unroll") for (int n = 0; n < NR; ++n)                              \
          acc[m][n] = __builtin_amdgcn_mfma_f32_16x16x32_bf16(af[m], bf[n], acc[m][n], 0, 0, 0); \
    }                                                                               \
  } while (0)

  STAGE(0, A0, B0);
#pragma unroll 1
  for (int kt = 0; kt < 14; kt += 2) {
    STAGE((kt + 1) * 64, A1, B1);
    PIPE_WAIT8; PIPE_BAR;
    __builtin_amdgcn_s_setprio(1);
    COMPUTE(A0, B0);
    __builtin_amdgcn_s_setprio(0);
    PIPE_ENDBAR;
    STAGE((kt + 2) * 64, A0, B0);
    PIPE_WAIT8; PIPE_BAR;
    __builtin_amdgcn_s_setprio(1);
    COMPUTE(A1, B1);
    __builtin_amdgcn_s_setprio(0);
    PIPE_ENDBAR;
  }
  STAGE(15 * 64, A1, B1);
  PIPE_WAIT8; PIPE_BAR;
  __builtin_amdgcn_s_setprio(1);
  COMPUTE(A0, B0);
  __builtin_amdgcn_s_setprio(0);
  PIPE_ENDBAR;
  PIPE_WAIT0; PIPE_BAR;
  __builtin_amdgcn_s_setprio(1);
  COMPUTE(A1, B1);
  __builtin_amdgcn_s_setprio(0);

#undef STAGE
#undef COMPUTE

#pragma unroll
  for (int n = 0; n < NR; ++n) {
    const int gc = n0 + wn * RSN + n * 16 + lr;
    const float bv = bias[gc];
#pragma unroll
    for (int m = 0; m < MR; ++m) {
      const int gr0 = m0 + wm * RSM + m * 16 + lg * 4;
#pragma unroll
      for (int r = 0; r < 4; ++r) {
        const float val = acc[m][n][r] + bv;
        if (F32OUT) Of[(size_t)(gr0 + r) * DM + gc] = val;
        else        O[(size_t)(gr0 + r) * DM + gc] = f2b(val);
      }
    }
  }
}

// ---------------------------------------------------------------------------
// Sliding-window attention v3: split-K.  Block = 256 thr = 4 warps covering
// 2 q-tiles of 32 rows; the two warps of a q-tile each process HALF of the
// key chunks (static-max softmax => unnormalized partials are additive),
// then combine via LDS.  Grid 1024 blocks -> 4096 waves (4/SIMD, was 2).
// Packing p->bf16 via __float22bfloat162_rn (v_cvt_pk_bf16_f32).
// Combine buffer aliases the (dead) Vt region, keeping LDS at 40KB.
// ---------------------------------------------------------------------------
__global__ __launch_bounds__(256, 4) void attn(
    const unsigned short* __restrict__ Q,
    const unsigned short* __restrict__ Km,
    const unsigned short* __restrict__ Vm,
    unsigned short* __restrict__ AO)
{
  const int warp = threadIdx.x >> 6;
  const int l = threadIdx.x & 63;
  const int qt = warp >> 1;        // q-tile within block
  const int half = warp & 1;       // key-split half
  const int qw0 = (blockIdx.x * 2 + qt) * 32;
  const int hD = blockIdx.y * DH;
  const int q = l & 31;
  const int hi = l >> 5;
  const int l31 = l & 31;
  const int vkey = (l & 15) * 2;
  const int vd0 = (l >> 4) * 16;

  __shared__ __align__(16) char SMEM[40960];
  unsigned short* vt0 = (unsigned short*)SMEM + warp * 2 * 2560;
  unsigned short* vt1 = vt0 + 2560;
  float* comb = (float*)SMEM;                       // [2 qt][64 lane][36]
  float* clsum = (float*)(SMEM + 2 * 64 * 36 * 4);  // [2 qt][64 lane]

  short8 qf[4];
  {
    const unsigned short* qp = Q + (size_t)(qw0 + q) * DM + hD + hi * 8;
#pragma unroll
    for (int ks = 0; ks < 4; ++ks) qf[ks] = *(const short8*)(qp + ks * 16);
  }

  f32x16 o0{}, o1{};
  float lsum = 0.f;

  const int kb0 = (qw0 >= WIN) ? (qw0 - WIN) : 0;
  const int nch = (qw0 + 32 - kb0) >> 5;
  const int nlo = nch >> 1;
  const int myn = half ? (nch - nlo) : nlo;
  const int kbh = kb0 + (half ? nlo : 0) * 32;

  short8 kfA[4], vfA[4], kfB[4], vfB[4];

#define LOADKV(kb_, kf_, vf_)                                                    \
  do {                                                                           \
    const unsigned short* kp_ = Km + (size_t)((kb_) + l31) * DM + hD + hi * 8;   \
    (kf_)[0] = *(const short8*)kp_;                                              \
    (kf_)[1] = *(const short8*)(kp_ + 16);                                       \
    (kf_)[2] = *(const short8*)(kp_ + 32);                                       \
    (kf_)[3] = *(const short8*)(kp_ + 48);                                       \
    const unsigned short* vp_ = Vm + (size_t)((kb_) + vkey) * DM + hD + vd0;     \
    (vf_)[0] = *(const short8*)vp_;                                              \
    (vf_)[1] = *(const short8*)(vp_ + 8);                                        \
    (vf_)[2] = *(const short8*)(vp_ + DM);                                       \
    (vf_)[3] = *(const short8*)(vp_ + DM + 8);                                   \
  } while (0)

#define PROCESS(kb_, kf_, vf_, vt_)                                             \
  do {                                                                          \
    const int kbv = (kb_);                                                      \
    _Pragma("unroll") for (int j = 0; j < 16; ++j) {                            \
      unsigned int wv = (unsigned int)(unsigned short)(vf_)[j >> 3][j & 7]      \
          | ((unsigned int)(unsigned short)(vf_)[2 + (j >> 3)][j & 7] << 16);   \
      *(unsigned int*)((vt_) + (vd0 + j) * 40 + vkey) = wv;                     \
    }                                                                           \
    f32x16 s{};                                                                 \
    _Pragma("unroll") for (int ks = 0; ks < 4; ++ks)                            \
      s = __builtin_amdgcn_mfma_f32_32x32x16_bf16((kf_)[ks], qf[ks], s, 0, 0, 0); \
    float p[16];                                                                \
    const bool isEdge = (kbv >= qw0) || (kbv + WIN - 32 < qw0);                 \
    if (isEdge) {                                                               \
      _Pragma("unroll") for (int r = 0; r < 16; ++r) {                          \
        const int key = kbv + (r & 3) + 8 * (r >> 2) + 4 * hi;                  \
        const int qg = qw0 + q;                                                 \
        const bool valid = (key <= qg) && (qg - key < WIN);                     \
        p[r] = valid ? __expf(s[r] * 0.125f) : 0.f;                             \
        lsum += p[r];                                                           \
      }                                                                         \
    } else {                                                                    \
      _Pragma("unroll") for (int r = 0; r < 16; ++r) {                          \
        p[r] = __expf(s[r] * 0.125f);                                           \
        lsum += p[r];                                                           \
      }                                                                         \
    }                                                                           \
    unsigned int u[8];                                                          \
    _Pragma("unroll") for (int t2 = 0; t2 < 4; ++t2) {                          \
      __hip_bfloat162 h0_ = __float22bfloat162_rn(make_float2(p[4 * t2], p[4 * t2 + 1])); \
      __hip_bfloat162 h1_ = __float22bfloat162_rn(make_float2(p[4 * t2 + 2], p[4 * t2 + 3])); \
      u[2 * t2]     = *(unsigned int*)&h0_;                                     \
      u[2 * t2 + 1] = *(unsigned int*)&h1_;                                     \
    }                                                                           \
    const unsigned int sd0 = hi ? u[0] : u[2], sd1 = hi ? u[1] : u[3];          \
    const unsigned int rc0 = __shfl_xor(sd0, 32, 64), rc1 = __shfl_xor(sd1, 32, 64); \
    const unsigned int sd2 = hi ? u[4] : u[6], sd3 = hi ? u[5] : u[7];          \
    const unsigned int rc2 = __shfl_xor(sd2, 32, 64), rc3 = __shfl_xor(sd3, 32, 64); \
    i32x4 pw0, pw1;                                                             \
    pw0[0] = hi ? rc0 : u[0]; pw0[1] = hi ? rc1 : u[1];                         \
    pw0[2] = hi ? u[2] : rc0; pw0[3] = hi ? u[3] : rc1;                         \
    pw1[0] = hi ? rc2 : u[4]; pw1[1] = hi ? rc3 : u[5];                         \
    pw1[2] = hi ? u[6] : rc2; pw1[3] = hi ? u[7] : rc3;                         \
    const short8 pf0 = *(const short8*)&pw0;                                    \
    const short8 pf1 = *(const short8*)&pw1;                                    \
    const short8 a00 = *(const short8*)((vt_) + l31 * 40 + hi * 8);             \
    const short8 a01 = *(const short8*)((vt_) + l31 * 40 + 16 + hi * 8);        \
    const short8 a10 = *(const short8*)((vt_) + (32 + l31) * 40 + hi * 8);      \
    const short8 a11 = *(const short8*)((vt_) + (32 + l31) * 40 + 16 + hi * 8); \
    o0 = __builtin_amdgcn_mfma_f32_32x32x16_bf16(a00, pf0, o0, 0, 0, 0);        \
    o0 = __builtin_amdgcn_mfma_f32_32x32x16_bf16(a01, pf1, o0, 0, 0, 0);        \
    o1 = __builtin_amdgcn_mfma_f32_32x32x16_bf16(a10, pf0, o1, 0, 0, 0);        \
    o1 = __builtin_amdgcn_mfma_f32_32x32x16_bf16(a11, pf1, o1, 0, 0, 0);        \
  } while (0)

  LOADKV(kbh, kfA, vfA);
  int c = 0;
#pragma unroll 1
  for (; c + 2 <= myn; c += 2) {
    const int kb = kbh + c * 32;
    LOADKV(kb + 32, kfB, vfB);
    PROCESS(kb, kfA, vfA, vt0);
    if (c + 2 < myn) LOADKV(kb + 64, kfA, vfA);
    PROCESS(kb + 32, kfB, vfB, vt1);
  }
  if (c < myn) PROCESS(kbh + c * 32, kfA, vfA, vt0);

#undef LOADKV
#undef PROCESS

  // ---- split-K combine (Vt region is dead after this barrier) ----
  __syncthreads();
  if (half == 0) {
    float* cb = comb + (qt * 64 + l) * 36;
#pragma unroll
    for (int t2 = 0; t2 < 4; ++t2) {
      *(f32x4*)(cb + t2 * 4)      = (f32x4){o0[4*t2], o0[4*t2+1], o0[4*t2+2], o0[4*t2+3]};
      *(f32x4*)(cb + 16 + t2 * 4) = (f32x4){o1[4*t2], o1[4*t2+1], o1[4*t2+2], o1[4*t2+3]};
    }
    clsum[qt * 64 + l] = lsum;
  }
  __syncthreads();
  if (half == 1) {
    const float* cb = comb + (qt * 64 + l) * 36;
#pragma unroll
    for (int t2 = 0; t2 < 4; ++t2) {
      f32x4 pa = *(const f32x4*)(cb + t2 * 4);
      f32x4 pb = *(const f32x4*)(cb + 16 + t2 * 4);
#pragma unroll
      for (int j = 0; j < 4; ++j) { o0[4*t2+j] += pa[j]; o1[4*t2+j] += pb[j]; }
    }
    lsum += clsum[qt * 64 + l];
    lsum += __shfl_xor(lsum, 32, 64);
    const float inv = 1.f / lsum;
    unsigned short* aop = AO + (size_t)(qw0 + q) * DM + hD;
#pragma unroll
    for (int t2 = 0; t2 < 4; ++t2) {
      __hip_bfloat162 s0 = __float22bfloat162_rn(make_float2(o0[4*t2] * inv, o0[4*t2+1] * inv));
      __hip_bfloat162 s1 = __float22bfloat162_rn(make_float2(o0[4*t2+2] * inv, o0[4*t2+3] * inv));
      uint2 st; st.x = *(unsigned int*)&s0; st.y = *(unsigned int*)&s1;
      *(uint2*)(aop + 8 * t2 + 4 * hi) = st;
      __hip_bfloat162 s2 = __float22bfloat162_rn(make_float2(o1[4*t2] * inv, o1[4*t2+1] * inv));
      __hip_bfloat162 s3 = __float22bfloat162_rn(make_float2(o1[4*t2+2] * inv, o1[4*t2+3] * inv));
      uint2 st2; st2.x = *(unsigned int*)&s2; st2.y = *(unsigned int*)&s3;
      *(uint2*)(aop + 32 + 8 * t2 + 4 * hi) = st2;
    }
  }
}

// ---------------------------------------------------------------------------
extern "C" void kernel_launch(void* const* d_in, const int* in_sizes, int n_in,
                              void* d_out, int out_size, void* d_ws, size_t ws_size,
                              hipStream_t stream) {
  const float* x  = (const float*)d_in[0];
  const float* qw = (const float*)d_in[1];
  const float* qb = (const float*)d_in[2];
  const float* kw = (const float*)d_in[3];
  const float* kb = (const float*)d_in[4];
  const float* vw = (const float*)d_in[5];
  const float* vb = (const float*)d_in[6];
  const float* ow = (const float*)d_in[7];
  const float* ob = (const float*)d_in[8];

  const size_t SD = (size_t)S_LEN * DM;
  unsigned short* Qb  = (unsigned short*)d_ws;
  unsigned short* Kb  = Qb + SD;
  unsigned short* Vb  = Kb + SD;
  unsigned short* AOb = Vb + SD;
  unsigned short* Xb  = AOb + SD;
  unsigned short* Wcv = Xb + SD;

  cvt_all<<<dim3(2048, 5), 256, 0, stream>>>(x, qw, kw, vw, ow, Xb, Wcv);
  gemm_bt<256, 256, 2, 4, false><<<dim3(16, 4, 3), 512, 0, stream>>>(
      Xb, Wcv, qb, kb, vb, Qb, nullptr);
  attn<<<dim3(S_LEN / 64, NH), 256, 0, stream>>>(Qb, Kb, Vb, AOb);
  gemm_bt<128, 128, 2, 2, true><<<dim3(32, 8, 1), 256, 0, stream>>>(
      AOb, Wcv + (size_t)3 * DM * DM, ob, ob, ob, nullptr, (float*)d_out);
}

// Round 9
// 89.014 us; speedup vs baseline: 1.3911x; 1.3911x over previous
//
#include <hip/hip_runtime.h>
#include <hip/hip_bf16.h>

typedef __attribute__((ext_vector_type(4))) float f32x4;
typedef __attribute__((ext_vector_type(16))) float f32x16;
typedef __attribute__((ext_vector_type(8))) short short8;
typedef __attribute__((ext_vector_type(4))) int i32x4;

#define S_LEN 4096
#define DM    1024
#define NH    16
#define DH    64
#define WIN   256

__device__ inline unsigned short f2b(float f) {
  unsigned int x = __float_as_uint(f);
  unsigned int r = (x + 0x7fffu + ((x >> 16) & 1u)) >> 16;
  return (unsigned short)r;
}

__device__ inline void gload_lds16(const void* g, void* l) {
  __builtin_amdgcn_global_load_lds(
      (const __attribute__((address_space(1))) void*)g,
      (__attribute__((address_space(3))) void*)l, 16, 0, 0);
}

// ---------------------------------------------------------------------------
// Convert X and the 4 weight matrices f32 -> bf16.
// ---------------------------------------------------------------------------
__global__ __launch_bounds__(256) void cvt_all(
    const float* __restrict__ x,
    const float* __restrict__ qw, const float* __restrict__ kw,
    const float* __restrict__ vw, const float* __restrict__ ow,
    unsigned short* __restrict__ Xb, unsigned short* __restrict__ Wb)
{
  const int y = blockIdx.y;
  const float* src;
  unsigned short* dst;
  int n8;
  if (y == 0) { src = x; dst = Xb; n8 = (S_LEN * DM) / 8; }
  else {
    src = (y == 1) ? qw : (y == 2) ? kw : (y == 3) ? vw : ow;
    dst = Wb + (size_t)(y - 1) * DM * DM;
    n8 = (DM * DM) / 8;
  }
  const int i = blockIdx.x * 256 + threadIdx.x;
  if (i >= n8) return;
  const float4* s4 = (const float4*)src + (size_t)i * 2;
  float4 a = s4[0], b = s4[1];
  short8 v;
  v[0] = f2b(a.x); v[1] = f2b(a.y); v[2] = f2b(a.z); v[3] = f2b(a.w);
  v[4] = f2b(b.x); v[5] = f2b(b.y); v[6] = f2b(b.z); v[7] = f2b(b.w);
  *(short8*)(dst + (size_t)i * 8) = v;
}

// ---------------------------------------------------------------------------
// Deep-pipelined GEMM (round-4/5 version, measured best: qkv 40.5us, 0 bank
// conflicts): BK=64, double-buffered LDS, counted vmcnt(8), swizzled layout
// (col bits 4-6 ^= row bits 0-2 via pre-swizzled global src), setprio.
// ---------------------------------------------------------------------------
#define PIPE_WAIT8  asm volatile("s_waitcnt vmcnt(8)" ::: "memory")
#define PIPE_WAIT0  asm volatile("s_waitcnt vmcnt(0)" ::: "memory")
#define PIPE_BAR    do { __builtin_amdgcn_s_barrier(); __builtin_amdgcn_sched_barrier(0); } while (0)
#define PIPE_ENDBAR do { __builtin_amdgcn_sched_barrier(0); __builtin_amdgcn_s_barrier(); \
                         __builtin_amdgcn_sched_barrier(0); } while (0)

template<int BM, int BN, int NWM, int NWN, bool F32OUT>
__global__ __launch_bounds__(NWM* NWN * 64, 1) void gemm_bt(
    const unsigned short* __restrict__ A,
    const unsigned short* __restrict__ Wb,
    const float* __restrict__ b0, const float* __restrict__ b1, const float* __restrict__ b2,
    unsigned short* __restrict__ Obf,
    float* __restrict__ Of)
{
  constexpr int THREADS = NWM * NWN * 64;
  constexpr int MR = BM / (NWM * 16);
  constexpr int NR = BN / (NWN * 16);
  constexpr int RSM = BM / NWM;
  constexpr int RSN = BN / NWN;
  constexpr int REG = BM * 64;
  static_assert(BM == BN, "");
  static_assert((BM * 64 * 2) / (THREADS * 16) == 4, "4 staging rounds");

  const int z = blockIdx.z;
  const unsigned short* Bmat = Wb + (size_t)z * DM * DM;
  const float* bias = (z == 0) ? b0 : (z == 1) ? b1 : b2;
  unsigned short* O = Obf + (size_t)z * S_LEN * DM;

  __shared__ __align__(16) unsigned short LDS[4 * REG];
  unsigned short* A0 = LDS;
  unsigned short* A1 = LDS + REG;
  unsigned short* B0 = LDS + 2 * REG;
  unsigned short* B1 = LDS + 3 * REG;

  const int t = threadIdx.x;
  const int lane = t & 63, w = t >> 6;
  const int wm = w / NWN, wn = w % NWN;
  const int lr = lane & 15, lg = lane >> 4;
  const int m0 = blockIdx.x * BM, n0 = blockIdx.y * BN;

  int srow[4], scol[4], sbase[4];
#pragma unroll
  for (int i = 0; i < 4; ++i) {
    const int bo = (i * THREADS + w * 64) * 16;
    const int o = bo + lane * 16;
    const int row = o >> 7, colb = o & 127;
    const int colp = colb ^ ((row & 3) << 4) ^ (((row >> 2) & 1) << 6);
    srow[i] = row; scol[i] = colp >> 1; sbase[i] = bo >> 1;
  }

#define STAGE(e0, lA, lB)                                                           \
  do {                                                                              \
    _Pragma("unroll") for (int i = 0; i < 4; ++i) {                                 \
      gload_lds16(A + (size_t)(m0 + srow[i]) * DM + (e0) + scol[i], (lA) + sbase[i]); \
      gload_lds16(Bmat + (size_t)(n0 + srow[i]) * DM + (e0) + scol[i], (lB) + sbase[i]); \
    }                                                                               \
  } while (0)

  f32x4 acc[MR][NR];
#pragma unroll
  for (int m = 0; m < MR; ++m)
#pragma unroll
    for (int n = 0; n < NR; ++n) acc[m][n] = (f32x4){0.f, 0.f, 0.f, 0.f};

  const int xor6l = ((lr >> 2) & 1) << 6;
  const int xor45 = (lg << 4) ^ ((lr & 3) << 4);

#define COMPUTE(sAp, sBp)                                                           \
  do {                                                                              \
    _Pragma("unroll") for (int kk = 0; kk < 2; ++kk) {                              \
      const int coff = ((kk << 6) ^ xor6l) + xor45;                                 \
      short8 af[MR], bf[NR];                                                        \
      _Pragma("unroll") for (int m = 0; m < MR; ++m)                                \
        af[m] = *(const short8*)((const char*)(sAp) + (wm * RSM + m * 16 + lr) * 128 + coff); \
      _Pragma("unroll") for (int n = 0; n < NR; ++n)                                \
        bf[n] = *(const short8*)((const char*)(sBp) + (wn * RSN + n * 16 + lr) * 128 + coff); \
      _Pragma("unroll") for (int m = 0; m < MR; ++m)                                \
        _Pragma("unroll") for (int n = 0; n < NR; ++n)                              \
          acc[m][n] = __builtin_amdgcn_mfma_f32_16x16x32_bf16(af[m], bf[n], acc[m][n], 0, 0, 0); \
    }                                                                               \
  } while (0)

  STAGE(0, A0, B0);
#pragma unroll 1
  for (int kt = 0; kt < 14; kt += 2) {
    STAGE((kt + 1) * 64, A1, B1);
    PIPE_WAIT8; PIPE_BAR;
    __builtin_amdgcn_s_setprio(1);
    COMPUTE(A0, B0);
    __builtin_amdgcn_s_setprio(0);
    PIPE_ENDBAR;
    STAGE((kt + 2) * 64, A0, B0);
    PIPE_WAIT8; PIPE_BAR;
    __builtin_amdgcn_s_setprio(1);
    COMPUTE(A1, B1);
    __builtin_amdgcn_s_setprio(0);
    PIPE_ENDBAR;
  }
  STAGE(15 * 64, A1, B1);
  PIPE_WAIT8; PIPE_BAR;
  __builtin_amdgcn_s_setprio(1);
  COMPUTE(A0, B0);
  __builtin_amdgcn_s_setprio(0);
  PIPE_ENDBAR;
  PIPE_WAIT0; PIPE_BAR;
  __builtin_amdgcn_s_setprio(1);
  COMPUTE(A1, B1);
  __builtin_amdgcn_s_setprio(0);

#undef STAGE
#undef COMPUTE

#pragma unroll
  for (int n = 0; n < NR; ++n) {
    const int gc = n0 + wn * RSN + n * 16 + lr;
    const float bv = bias[gc];
#pragma unroll
    for (int m = 0; m < MR; ++m) {
      const int gr0 = m0 + wm * RSM + m * 16 + lg * 4;
#pragma unroll
      for (int r = 0; r < 4; ++r) {
        const float val = acc[m][n][r] + bv;
        if (F32OUT) Of[(size_t)(gr0 + r) * DM + gc] = val;
        else        O[(size_t)(gr0 + r) * DM + gc] = f2b(val);
      }
    }
  }
}

// ---------------------------------------------------------------------------
// Sliding-window attention v3b: split-K, NO min-waves launch bound (round-7's
// `,4` capped unified VGPR+AGPR at 128 -> spill -> 138MB scratch traffic).
// Natural allocation ~110-130 regs; LDS 40KB allows 4 blocks/CU, grid 1024
// blocks x 4 waves = 4096 waves lifts occupancy 2/SIMD -> 3-4/SIMD.
// ---------------------------------------------------------------------------
__global__ __launch_bounds__(256) void attn(
    const unsigned short* __restrict__ Q,
    const unsigned short* __restrict__ Km,
    const unsigned short* __restrict__ Vm,
    unsigned short* __restrict__ AO)
{
  const int warp = threadIdx.x >> 6;
  const int l = threadIdx.x & 63;
  const int qt = warp >> 1;        // q-tile within block
  const int half = warp & 1;       // key-split half
  const int qw0 = (blockIdx.x * 2 + qt) * 32;
  const int hD = blockIdx.y * DH;
  const int q = l & 31;
  const int hi = l >> 5;
  const int l31 = l & 31;
  const int vkey = (l & 15) * 2;
  const int vd0 = (l >> 4) * 16;

  __shared__ __align__(16) char SMEM[40960];
  unsigned short* vt0 = (unsigned short*)SMEM + warp * 2 * 2560;
  unsigned short* vt1 = vt0 + 2560;
  float* comb = (float*)SMEM;                       // [2 qt][64 lane][36]
  float* clsum = (float*)(SMEM + 2 * 64 * 36 * 4);  // [2 qt][64 lane]

  short8 qf[4];
  {
    const unsigned short* qp = Q + (size_t)(qw0 + q) * DM + hD + hi * 8;
#pragma unroll
    for (int ks = 0; ks < 4; ++ks) qf[ks] = *(const short8*)(qp + ks * 16);
  }

  f32x16 o0{}, o1{};
  float lsum = 0.f;

  const int kb0 = (qw0 >= WIN) ? (qw0 - WIN) : 0;
  const int nch = (qw0 + 32 - kb0) >> 5;
  const int nlo = nch >> 1;
  const int myn = half ? (nch - nlo) : nlo;
  const int kbh = kb0 + (half ? nlo : 0) * 32;

  short8 kfA[4], vfA[4], kfB[4], vfB[4];

#define LOADKV(kb_, kf_, vf_)                                                    \
  do {                                                                           \
    const unsigned short* kp_ = Km + (size_t)((kb_) + l31) * DM + hD + hi * 8;   \
    (kf_)[0] = *(const short8*)kp_;                                              \
    (kf_)[1] = *(const short8*)(kp_ + 16);                                       \
    (kf_)[2] = *(const short8*)(kp_ + 32);                                       \
    (kf_)[3] = *(const short8*)(kp_ + 48);                                       \
    const unsigned short* vp_ = Vm + (size_t)((kb_) + vkey) * DM + hD + vd0;     \
    (vf_)[0] = *(const short8*)vp_;                                              \
    (vf_)[1] = *(const short8*)(vp_ + 8);                                        \
    (vf_)[2] = *(const short8*)(vp_ + DM);                                       \
    (vf_)[3] = *(const short8*)(vp_ + DM + 8);                                   \
  } while (0)

#define PROCESS(kb_, kf_, vf_, vt_)                                             \
  do {                                                                          \
    const int kbv = (kb_);                                                      \
    _Pragma("unroll") for (int j = 0; j < 16; ++j) {                            \
      unsigned int wv = (unsigned int)(unsigned short)(vf_)[j >> 3][j & 7]      \
          | ((unsigned int)(unsigned short)(vf_)[2 + (j >> 3)][j & 7] << 16);   \
      *(unsigned int*)((vt_) + (vd0 + j) * 40 + vkey) = wv;                     \
    }                                                                           \
    f32x16 s{};                                                                 \
    _Pragma("unroll") for (int ks = 0; ks < 4; ++ks)                            \
      s = __builtin_amdgcn_mfma_f32_32x32x16_bf16((kf_)[ks], qf[ks], s, 0, 0, 0); \
    float p[16];                                                                \
    const bool isEdge = (kbv >= qw0) || (kbv + WIN - 32 < qw0);                 \
    if (isEdge) {                                                               \
      _Pragma("unroll") for (int r = 0; r < 16; ++r) {                          \
        const int key = kbv + (r & 3) + 8 * (r >> 2) + 4 * hi;                  \
        const int qg = qw0 + q;                                                 \
        const bool valid = (key <= qg) && (qg - key < WIN);                     \
        p[r] = valid ? __expf(s[r] * 0.125f) : 0.f;                             \
        lsum += p[r];                                                           \
      }                                                                         \
    } else {                                                                    \
      _Pragma("unroll") for (int r = 0; r < 16; ++r) {                          \
        p[r] = __expf(s[r] * 0.125f);                                           \
        lsum += p[r];                                                           \
      }                                                                         \
    }                                                                           \
    unsigned int u[8];                                                          \
    _Pragma("unroll") for (int t2 = 0; t2 < 4; ++t2) {                          \
      __hip_bfloat162 h0_ = __float22bfloat162_rn(make_float2(p[4 * t2], p[4 * t2 + 1])); \
      __hip_bfloat162 h1_ = __float22bfloat162_rn(make_float2(p[4 * t2 + 2], p[4 * t2 + 3])); \
      u[2 * t2]     = *(unsigned int*)&h0_;                                     \
      u[2 * t2 + 1] = *(unsigned int*)&h1_;                                     \
    }                                                                           \
    const unsigned int sd0 = hi ? u[0] : u[2], sd1 = hi ? u[1] : u[3];          \
    const unsigned int rc0 = __shfl_xor(sd0, 32, 64), rc1 = __shfl_xor(sd1, 32, 64); \
    const unsigned int sd2 = hi ? u[4] : u[6], sd3 = hi ? u[5] : u[7];          \
    const unsigned int rc2 = __shfl_xor(sd2, 32, 64), rc3 = __shfl_xor(sd3, 32, 64); \
    i32x4 pw0, pw1;                                                             \
    pw0[0] = hi ? rc0 : u[0]; pw0[1] = hi ? rc1 : u[1];                         \
    pw0[2] = hi ? u[2] : rc0; pw0[3] = hi ? u[3] : rc1;                         \
    pw1[0] = hi ? rc2 : u[4]; pw1[1] = hi ? rc3 : u[5];                         \
    pw1[2] = hi ? u[6] : rc2; pw1[3] = hi ? u[7] : rc3;                         \
    const short8 pf0 = *(const short8*)&pw0;                                    \
    const short8 pf1 = *(const short8*)&pw1;                                    \
    const short8 a00 = *(const short8*)((vt_) + l31 * 40 + hi * 8);             \
    const short8 a01 = *(const short8*)((vt_) + l31 * 40 + 16 + hi * 8);        \
    const short8 a10 = *(const short8*)((vt_) + (32 + l31) * 40 + hi * 8);      \
    const short8 a11 = *(const short8*)((vt_) + (32 + l31) * 40 + 16 + hi * 8); \
    o0 = __builtin_amdgcn_mfma_f32_32x32x16_bf16(a00, pf0, o0, 0, 0, 0);        \
    o0 = __builtin_amdgcn_mfma_f32_32x32x16_bf16(a01, pf1, o0, 0, 0, 0);        \
    o1 = __builtin_amdgcn_mfma_f32_32x32x16_bf16(a10, pf0, o1, 0, 0, 0);        \
    o1 = __builtin_amdgcn_mfma_f32_32x32x16_bf16(a11, pf1, o1, 0, 0, 0);        \
  } while (0)

  LOADKV(kbh, kfA, vfA);
  int c = 0;
#pragma unroll 1
  for (; c + 2 <= myn; c += 2) {
    const int kb = kbh + c * 32;
    LOADKV(kb + 32, kfB, vfB);
    PROCESS(kb, kfA, vfA, vt0);
    if (c + 2 < myn) LOADKV(kb + 64, kfA, vfA);
    PROCESS(kb + 32, kfB, vfB, vt1);
  }
  if (c < myn) PROCESS(kbh + c * 32, kfA, vfA, vt0);

#undef LOADKV
#undef PROCESS

  // ---- split-K combine (Vt region is dead after this barrier) ----
  __syncthreads();
  if (half == 0) {
    float* cb = comb + (qt * 64 + l) * 36;
#pragma unroll
    for (int t2 = 0; t2 < 4; ++t2) {
      *(f32x4*)(cb + t2 * 4)      = (f32x4){o0[4*t2], o0[4*t2+1], o0[4*t2+2], o0[4*t2+3]};
      *(f32x4*)(cb + 16 + t2 * 4) = (f32x4){o1[4*t2], o1[4*t2+1], o1[4*t2+2], o1[4*t2+3]};
    }
    clsum[qt * 64 + l] = lsum;
  }
  __syncthreads();
  if (half == 1) {
    const float* cb = comb + (qt * 64 + l) * 36;
#pragma unroll
    for (int t2 = 0; t2 < 4; ++t2) {
      f32x4 pa = *(const f32x4*)(cb + t2 * 4);
      f32x4 pb = *(const f32x4*)(cb + 16 + t2 * 4);
#pragma unroll
      for (int j = 0; j < 4; ++j) { o0[4*t2+j] += pa[j]; o1[4*t2+j] += pb[j]; }
    }
    lsum += clsum[qt * 64 + l];
    lsum += __shfl_xor(lsum, 32, 64);
    const float inv = 1.f / lsum;
    unsigned short* aop = AO + (size_t)(qw0 + q) * DM + hD;
#pragma unroll
    for (int t2 = 0; t2 < 4; ++t2) {
      __hip_bfloat162 s0 = __float22bfloat162_rn(make_float2(o0[4*t2] * inv, o0[4*t2+1] * inv));
      __hip_bfloat162 s1 = __float22bfloat162_rn(make_float2(o0[4*t2+2] * inv, o0[4*t2+3] * inv));
      uint2 st; st.x = *(unsigned int*)&s0; st.y = *(unsigned int*)&s1;
      *(uint2*)(aop + 8 * t2 + 4 * hi) = st;
      __hip_bfloat162 s2 = __float22bfloat162_rn(make_float2(o1[4*t2] * inv, o1[4*t2+1] * inv));
      __hip_bfloat162 s3 = __float22bfloat162_rn(make_float2(o1[4*t2+2] * inv, o1[4*t2+3] * inv));
      uint2 st2; st2.x = *(unsigned int*)&s2; st2.y = *(unsigned int*)&s3;
      *(uint2*)(aop + 32 + 8 * t2 + 4 * hi) = st2;
    }
  }
}

// ---------------------------------------------------------------------------
extern "C" void kernel_launch(void* const* d_in, const int* in_sizes, int n_in,
                              void* d_out, int out_size, void* d_ws, size_t ws_size,
                              hipStream_t stream) {
  const float* x  = (const float*)d_in[0];
  const float* qw = (const float*)d_in[1];
  const float* qb = (const float*)d_in[2];
  const float* kw = (const float*)d_in[3];
  const float* kb = (const float*)d_in[4];
  const float* vw = (const float*)d_in[5];
  const float* vb = (const float*)d_in[6];
  const float* ow = (const float*)d_in[7];
  const float* ob = (const float*)d_in[8];

  const size_t SD = (size_t)S_LEN * DM;
  unsigned short* Qb  = (unsigned short*)d_ws;
  unsigned short* Kb  = Qb + SD;
  unsigned short* Vb  = Kb + SD;
  unsigned short* AOb = Vb + SD;
  unsigned short* Xb  = AOb + SD;
  unsigned short* Wcv = Xb + SD;

  cvt_all<<<dim3(2048, 5), 256, 0, stream>>>(x, qw, kw, vw, ow, Xb, Wcv);
  gemm_bt<256, 256, 2, 4, false><<<dim3(16, 4, 3), 512, 0, stream>>>(
      Xb, Wcv, qb, kb, vb, Qb, nullptr);
  attn<<<dim3(S_LEN / 64, NH), 256, 0, stream>>>(Qb, Kb, Vb, AOb);
  gemm_bt<128, 128, 2, 2, true><<<dim3(32, 8, 1), 256, 0, stream>>>(
      AOb, Wcv + (size_t)3 * DM * DM, ob, ob, ob, nullptr, (float*)d_out);
}

// Round 10
// 81.675 us; speedup vs baseline: 1.5161x; 1.0898x over previous
//
#include <hip/hip_runtime.h>
#include <hip/hip_bf16.h>

typedef __attribute__((ext_vector_type(4))) float f32x4;
typedef __attribute__((ext_vector_type(16))) float f32x16;
typedef __attribute__((ext_vector_type(8))) short short8;
typedef __attribute__((ext_vector_type(4))) int i32x4;

#define S_LEN 4096
#define DM    1024
#define NH    16
#define DH    64
#define WIN   256

__device__ inline unsigned short f2b(float f) {
  unsigned int x = __float_as_uint(f);
  unsigned int r = (x + 0x7fffu + ((x >> 16) & 1u)) >> 16;
  return (unsigned short)r;
}

__device__ inline void gload_lds16(const void* g, void* l) {
  __builtin_amdgcn_global_load_lds(
      (const __attribute__((address_space(1))) void*)g,
      (__attribute__((address_space(3))) void*)l, 16, 0, 0);
}

// ---------------------------------------------------------------------------
// Convert X and the 4 weight matrices f32 -> bf16.
// ---------------------------------------------------------------------------
__global__ __launch_bounds__(256) void cvt_all(
    const float* __restrict__ x,
    const float* __restrict__ qw, const float* __restrict__ kw,
    const float* __restrict__ vw, const float* __restrict__ ow,
    unsigned short* __restrict__ Xb, unsigned short* __restrict__ Wb)
{
  const int y = blockIdx.y;
  const float* src;
  unsigned short* dst;
  int n8;
  if (y == 0) { src = x; dst = Xb; n8 = (S_LEN * DM) / 8; }
  else {
    src = (y == 1) ? qw : (y == 2) ? kw : (y == 3) ? vw : ow;
    dst = Wb + (size_t)(y - 1) * DM * DM;
    n8 = (DM * DM) / 8;
  }
  const int i = blockIdx.x * 256 + threadIdx.x;
  if (i >= n8) return;
  const float4* s4 = (const float4*)src + (size_t)i * 2;
  float4 a = s4[0], b = s4[1];
  short8 v;
  v[0] = f2b(a.x); v[1] = f2b(a.y); v[2] = f2b(a.z); v[3] = f2b(a.w);
  v[4] = f2b(b.x); v[5] = f2b(b.y); v[6] = f2b(b.z); v[7] = f2b(b.w);
  *(short8*)(dst + (size_t)i * 8) = v;
}

#define PIPE_WAIT8  asm volatile("s_waitcnt vmcnt(8)" ::: "memory")
#define PIPE_WAIT7  asm volatile("s_waitcnt vmcnt(7)" ::: "memory")
#define PIPE_WAIT0  asm volatile("s_waitcnt vmcnt(0)" ::: "memory")
#define PIPE_BAR    do { __builtin_amdgcn_s_barrier(); __builtin_amdgcn_sched_barrier(0); } while (0)
#define PIPE_ENDBAR do { __builtin_amdgcn_sched_barrier(0); __builtin_amdgcn_s_barrier(); \
                         __builtin_amdgcn_sched_barrier(0); } while (0)

// ---------------------------------------------------------------------------
// Fused QKV GEMM: one 4096x3072 GEMM (weights contiguous in Wcv).
// BM=256, BN=192 -> grid 16x16 = 256 blocks = EXACTLY 1/CU (prev 192/256
// blocks left 25% of the chip idle).  Same proven 2-phase counted-vmcnt
// schedule; 7 loads/stage -> vmcnt(7).  8 waves (2M x 4N), wave tile 128x48,
// acc 8x3 (~170 VGPR, 2 waves/SIMD).
// ---------------------------------------------------------------------------
__global__ __launch_bounds__(512, 1) void gemm_qkv_fused(
    const unsigned short* __restrict__ A,    // Xb [4096][1024]
    const unsigned short* __restrict__ W,    // Wcv rows 0..3071 = q,k,v
    const float* __restrict__ bq, const float* __restrict__ bk, const float* __restrict__ bv,
    unsigned short* __restrict__ Qb)         // K at +SD, V at +2SD
{
  constexpr int BM = 256, BN = 192;
  constexpr int REGA = BM * 64;
  constexpr int BUF = REGA + BN * 64;
  __shared__ __align__(16) unsigned short LDS[2 * BUF];
  unsigned short* A0 = LDS;
  unsigned short* B0 = LDS + REGA;
  unsigned short* A1 = LDS + BUF;
  unsigned short* B1 = LDS + BUF + REGA;

  const int t = threadIdx.x;
  const int lane = t & 63, w = t >> 6;
  const int wm = w >> 2, wn = w & 3;
  const int lr = lane & 15, lg = lane >> 4;
  const int m0 = blockIdx.x * BM, n0 = blockIdx.y * BN;

  // staging precompute (A: rounds 0..3, B: rounds 0..2; same linear->swizzle map)
  int sr[4], sc[4], sb[4];
#pragma unroll
  for (int i = 0; i < 4; ++i) {
    const int bo = (i * 512 + w * 64) * 16;
    const int o = bo + lane * 16;
    const int row = o >> 7, colb = o & 127;
    const int colp = colb ^ ((row & 3) << 4) ^ (((row >> 2) & 1) << 6);
    sr[i] = row; sc[i] = colp >> 1; sb[i] = bo >> 1;
  }

#define STAGE(e0, lA, lB)                                                           \
  do {                                                                              \
    _Pragma("unroll") for (int i = 0; i < 4; ++i)                                   \
      gload_lds16(A + (size_t)(m0 + sr[i]) * DM + (e0) + sc[i], (lA) + sb[i]);      \
    _Pragma("unroll") for (int i = 0; i < 3; ++i)                                   \
      gload_lds16(W + (size_t)(n0 + sr[i]) * DM + (e0) + sc[i], (lB) + sb[i]);      \
  } while (0)

  f32x4 acc[8][3];
#pragma unroll
  for (int m = 0; m < 8; ++m)
#pragma unroll
    for (int n = 0; n < 3; ++n) acc[m][n] = (f32x4){0.f, 0.f, 0.f, 0.f};

  const int xor6l = ((lr >> 2) & 1) << 6;
  const int xor45 = (lg << 4) ^ ((lr & 3) << 4);

#define COMPUTE(sAp, sBp)                                                           \
  do {                                                                              \
    _Pragma("unroll") for (int kk = 0; kk < 2; ++kk) {                              \
      const int coff = ((kk << 6) ^ xor6l) + xor45;                                 \
      short8 af[8], bf[3];                                                          \
      _Pragma("unroll") for (int m = 0; m < 8; ++m)                                 \
        af[m] = *(const short8*)((const char*)(sAp) + (wm * 128 + m * 16 + lr) * 128 + coff); \
      _Pragma("unroll") for (int n = 0; n < 3; ++n)                                 \
        bf[n] = *(const short8*)((const char*)(sBp) + (wn * 48 + n * 16 + lr) * 128 + coff); \
      _Pragma("unroll") for (int m = 0; m < 8; ++m)                                 \
        _Pragma("unroll") for (int n = 0; n < 3; ++n)                               \
          acc[m][n] = __builtin_amdgcn_mfma_f32_16x16x32_bf16(af[m], bf[n], acc[m][n], 0, 0, 0); \
    }                                                                               \
  } while (0)

  STAGE(0, A0, B0);
#pragma unroll 1
  for (int kt = 0; kt < 14; kt += 2) {
    STAGE((kt + 1) * 64, A1, B1);
    PIPE_WAIT7; PIPE_BAR;
    __builtin_amdgcn_s_setprio(1);
    COMPUTE(A0, B0);
    __builtin_amdgcn_s_setprio(0);
    PIPE_ENDBAR;
    STAGE((kt + 2) * 64, A0, B0);
    PIPE_WAIT7; PIPE_BAR;
    __builtin_amdgcn_s_setprio(1);
    COMPUTE(A1, B1);
    __builtin_amdgcn_s_setprio(0);
    PIPE_ENDBAR;
  }
  STAGE(15 * 64, A1, B1);
  PIPE_WAIT7; PIPE_BAR;
  __builtin_amdgcn_s_setprio(1);
  COMPUTE(A0, B0);
  __builtin_amdgcn_s_setprio(0);
  PIPE_ENDBAR;
  PIPE_WAIT0; PIPE_BAR;
  __builtin_amdgcn_s_setprio(1);
  COMPUTE(A1, B1);
  __builtin_amdgcn_s_setprio(0);

#undef STAGE
#undef COMPUTE

#pragma unroll
  for (int n = 0; n < 3; ++n) {
    const int gc = n0 + wn * 48 + n * 16 + lr;
    const int slice = gc >> 10, col = gc & 1023;
    const float* bp = (slice == 0) ? bq : (slice == 1) ? bk : bv;
    const float bv_ = bp[col];
    unsigned short* Obase = Qb + (size_t)slice * ((size_t)S_LEN * DM);
#pragma unroll
    for (int m = 0; m < 8; ++m) {
      const int gr0 = m0 + wm * 128 + m * 16 + lg * 4;
#pragma unroll
      for (int r = 0; r < 4; ++r)
        Obase[(size_t)(gr0 + r) * DM + col] = f2b(acc[m][n][r] + bv_);
    }
  }
}

// ---------------------------------------------------------------------------
// 128x128 2-phase pipelined GEMM for the output projection (unchanged,
// measured ~12us): BK=64, dbuf, vmcnt(8), swizzle, setprio.
// ---------------------------------------------------------------------------
__global__ __launch_bounds__(256, 1) void gemm_out(
    const unsigned short* __restrict__ A,
    const unsigned short* __restrict__ Bmat,
    const float* __restrict__ bias,
    float* __restrict__ Of)
{
  constexpr int REG = 128 * 64;
  __shared__ __align__(16) unsigned short LDS[4 * REG];
  unsigned short* A0 = LDS;
  unsigned short* A1 = LDS + REG;
  unsigned short* B0 = LDS + 2 * REG;
  unsigned short* B1 = LDS + 3 * REG;

  const int t = threadIdx.x;
  const int lane = t & 63, w = t >> 6;
  const int wm = w >> 1, wn = w & 1;
  const int lr = lane & 15, lg = lane >> 4;
  const int m0 = blockIdx.x * 128, n0 = blockIdx.y * 128;

  int sr[4], sc[4], sb[4];
#pragma unroll
  for (int i = 0; i < 4; ++i) {
    const int bo = (i * 256 + w * 64) * 16;
    const int o = bo + lane * 16;
    const int row = o >> 7, colb = o & 127;
    const int colp = colb ^ ((row & 3) << 4) ^ (((row >> 2) & 1) << 6);
    sr[i] = row; sc[i] = colp >> 1; sb[i] = bo >> 1;
  }

#define STAGE(e0, lA, lB)                                                           \
  do {                                                                              \
    _Pragma("unroll") for (int i = 0; i < 4; ++i) {                                 \
      gload_lds16(A + (size_t)(m0 + sr[i]) * DM + (e0) + sc[i], (lA) + sb[i]);      \
      gload_lds16(Bmat + (size_t)(n0 + sr[i]) * DM + (e0) + sc[i], (lB) + sb[i]);   \
    }                                                                               \
  } while (0)

  f32x4 acc[4][4];
#pragma unroll
  for (int m = 0; m < 4; ++m)
#pragma unroll
    for (int n = 0; n < 4; ++n) acc[m][n] = (f32x4){0.f, 0.f, 0.f, 0.f};

  const int xor6l = ((lr >> 2) & 1) << 6;
  const int xor45 = (lg << 4) ^ ((lr & 3) << 4);

#define COMPUTE(sAp, sBp)                                                           \
  do {                                                                              \
    _Pragma("unroll") for (int kk = 0; kk < 2; ++kk) {                              \
      const int coff = ((kk << 6) ^ xor6l) + xor45;                                 \
      short8 af[4], bf[4];                                                          \
      _Pragma("unroll") for (int m = 0; m < 4; ++m)                                 \
        af[m] = *(const short8*)((const char*)(sAp) + (wm * 64 + m * 16 + lr) * 128 + coff); \
      _Pragma("unroll") for (int n = 0; n < 4; ++n)                                 \
        bf[n] = *(const short8*)((const char*)(sBp) + (wn * 64 + n * 16 + lr) * 128 + coff); \
      _Pragma("unroll") for (int m = 0; m < 4; ++m)                                 \
        _Pragma("unroll") for (int n = 0; n < 4; ++n)                               \
          acc[m][n] = __builtin_amdgcn_mfma_f32_16x16x32_bf16(af[m], bf[n], acc[m][n], 0, 0, 0); \
    }                                                                               \
  } while (0)

  STAGE(0, A0, B0);
#pragma unroll 1
  for (int kt = 0; kt < 14; kt += 2) {
    STAGE((kt + 1) * 64, A1, B1);
    PIPE_WAIT8; PIPE_BAR;
    __builtin_amdgcn_s_setprio(1);
    COMPUTE(A0, B0);
    __builtin_amdgcn_s_setprio(0);
    PIPE_ENDBAR;
    STAGE((kt + 2) * 64, A0, B0);
    PIPE_WAIT8; PIPE_BAR;
    __builtin_amdgcn_s_setprio(1);
    COMPUTE(A1, B1);
    __builtin_amdgcn_s_setprio(0);
    PIPE_ENDBAR;
  }
  STAGE(15 * 64, A1, B1);
  PIPE_WAIT8; PIPE_BAR;
  __builtin_amdgcn_s_setprio(1);
  COMPUTE(A0, B0);
  __builtin_amdgcn_s_setprio(0);
  PIPE_ENDBAR;
  PIPE_WAIT0; PIPE_BAR;
  __builtin_amdgcn_s_setprio(1);
  COMPUTE(A1, B1);
  __builtin_amdgcn_s_setprio(0);

#undef STAGE
#undef COMPUTE

#pragma unroll
  for (int n = 0; n < 4; ++n) {
    const int gc = n0 + wn * 64 + n * 16 + lr;
    const float bv = bias[gc];
#pragma unroll
    for (int m = 0; m < 4; ++m) {
      const int gr0 = m0 + wm * 64 + m * 16 + lg * 4;
#pragma unroll
      for (int r = 0; r < 4; ++r)
        Of[(size_t)(gr0 + r) * DM + gc] = acc[m][n][r] + bv;
    }
  }
}

// ---------------------------------------------------------------------------
// Sliding-window attention v2 (round-6 proven version + cvt_pk packing):
// 1 warp per 32 q-rows, 32x32x16 MFMA, swapped QK^T, static-max softmax,
// zero barriers, per-warp private double-buffered V^T LDS, K/V prefetch.
// ---------------------------------------------------------------------------
__global__ __launch_bounds__(256) void attn(
    const unsigned short* __restrict__ Q,
    const unsigned short* __restrict__ Km,
    const unsigned short* __restrict__ Vm,
    unsigned short* __restrict__ AO)
{
  const int warp = threadIdx.x >> 6;
  const int l = threadIdx.x & 63;
  const int qw0 = (blockIdx.x * 4 + warp) * 32;
  const int hD = blockIdx.y * DH;
  const int q = l & 31;
  const int hi = l >> 5;
  const int l31 = l & 31;
  const int vkey = (l & 15) * 2;
  const int vd0 = (l >> 4) * 16;

  __shared__ __align__(16) unsigned short VtS[4][2][64 * 40];
  unsigned short* vt0 = &VtS[warp][0][0];
  unsigned short* vt1 = &VtS[warp][1][0];

  short8 qf[4];
  {
    const unsigned short* qp = Q + (size_t)(qw0 + q) * DM + hD + hi * 8;
#pragma unroll
    for (int ks = 0; ks < 4; ++ks) qf[ks] = *(const short8*)(qp + ks * 16);
  }

  f32x16 o0{}, o1{};
  float lsum = 0.f;

  const int kb0 = (qw0 >= WIN) ? (qw0 - WIN) : 0;
  const int nch = (qw0 + 32 - kb0) >> 5;

  short8 kfA[4], vfA[4], kfB[4], vfB[4];

#define LOADKV(kb_, kf_, vf_)                                                    \
  do {                                                                           \
    const unsigned short* kp_ = Km + (size_t)((kb_) + l31) * DM + hD + hi * 8;   \
    (kf_)[0] = *(const short8*)kp_;                                              \
    (kf_)[1] = *(const short8*)(kp_ + 16);                                       \
    (kf_)[2] = *(const short8*)(kp_ + 32);                                       \
    (kf_)[3] = *(const short8*)(kp_ + 48);                                       \
    const unsigned short* vp_ = Vm + (size_t)((kb_) + vkey) * DM + hD + vd0;     \
    (vf_)[0] = *(const short8*)vp_;                                              \
    (vf_)[1] = *(const short8*)(vp_ + 8);                                        \
    (vf_)[2] = *(const short8*)(vp_ + DM);                                       \
    (vf_)[3] = *(const short8*)(vp_ + DM + 8);                                   \
  } while (0)

#define PROCESS(kb_, kf_, vf_, vt_)                                             \
  do {                                                                          \
    const int kbv = (kb_);                                                      \
    _Pragma("unroll") for (int j = 0; j < 16; ++j) {                            \
      unsigned int wv = (unsigned int)(unsigned short)(vf_)[j >> 3][j & 7]      \
          | ((unsigned int)(unsigned short)(vf_)[2 + (j >> 3)][j & 7] << 16);   \
      *(unsigned int*)((vt_) + (vd0 + j) * 40 + vkey) = wv;                     \
    }                                                                           \
    f32x16 s{};                                                                 \
    _Pragma("unroll") for (int ks = 0; ks < 4; ++ks)                            \
      s = __builtin_amdgcn_mfma_f32_32x32x16_bf16((kf_)[ks], qf[ks], s, 0, 0, 0); \
    float p[16];                                                                \
    const bool isEdge = (kbv >= qw0) || (kbv + WIN - 32 < qw0);                 \
    if (isEdge) {                                                               \
      _Pragma("unroll") for (int r = 0; r < 16; ++r) {                          \
        const int key = kbv + (r & 3) + 8 * (r >> 2) + 4 * hi;                  \
        const int qg = qw0 + q;                                                 \
        const bool valid = (key <= qg) && (qg - key < WIN);                     \
        p[r] = valid ? __expf(s[r] * 0.125f) : 0.f;                             \
        lsum += p[r];                                                           \
      }                                                                         \
    } else {                                                                    \
      _Pragma("unroll") for (int r = 0; r < 16; ++r) {                          \
        p[r] = __expf(s[r] * 0.125f);                                           \
        lsum += p[r];                                                           \
      }                                                                         \
    }                                                                           \
    unsigned int u[8];                                                          \
    _Pragma("unroll") for (int t2 = 0; t2 < 4; ++t2) {                          \
      __hip_bfloat162 h0_ = __float22bfloat162_rn(make_float2(p[4 * t2], p[4 * t2 + 1])); \
      __hip_bfloat162 h1_ = __float22bfloat162_rn(make_float2(p[4 * t2 + 2], p[4 * t2 + 3])); \
      u[2 * t2]     = *(unsigned int*)&h0_;                                     \
      u[2 * t2 + 1] = *(unsigned int*)&h1_;                                     \
    }                                                                           \
    const unsigned int sd0 = hi ? u[0] : u[2], sd1 = hi ? u[1] : u[3];          \
    const unsigned int rc0 = __shfl_xor(sd0, 32, 64), rc1 = __shfl_xor(sd1, 32, 64); \
    const unsigned int sd2 = hi ? u[4] : u[6], sd3 = hi ? u[5] : u[7];          \
    const unsigned int rc2 = __shfl_xor(sd2, 32, 64), rc3 = __shfl_xor(sd3, 32, 64); \
    i32x4 pw0, pw1;                                                             \
    pw0[0] = hi ? rc0 : u[0]; pw0[1] = hi ? rc1 : u[1];                         \
    pw0[2] = hi ? u[2] : rc0; pw0[3] = hi ? u[3] : rc1;                         \
    pw1[0] = hi ? rc2 : u[4]; pw1[1] = hi ? rc3 : u[5];                         \
    pw1[2] = hi ? u[6] : rc2; pw1[3] = hi ? u[7] : rc3;                         \
    const short8 pf0 = *(const short8*)&pw0;                                    \
    const short8 pf1 = *(const short8*)&pw1;                                    \
    const short8 a00 = *(const short8*)((vt_) + l31 * 40 + hi * 8);             \
    const short8 a01 = *(const short8*)((vt_) + l31 * 40 + 16 + hi * 8);        \
    const short8 a10 = *(const short8*)((vt_) + (32 + l31) * 40 + hi * 8);      \
    const short8 a11 = *(const short8*)((vt_) + (32 + l31) * 40 + 16 + hi * 8); \
    o0 = __builtin_amdgcn_mfma_f32_32x32x16_bf16(a00, pf0, o0, 0, 0, 0);        \
    o0 = __builtin_amdgcn_mfma_f32_32x32x16_bf16(a01, pf1, o0, 0, 0, 0);        \
    o1 = __builtin_amdgcn_mfma_f32_32x32x16_bf16(a10, pf0, o1, 0, 0, 0);        \
    o1 = __builtin_amdgcn_mfma_f32_32x32x16_bf16(a11, pf1, o1, 0, 0, 0);        \
  } while (0)

  LOADKV(kb0, kfA, vfA);
  int c = 0;
#pragma unroll 1
  for (; c + 2 <= nch; c += 2) {
    const int kb = kb0 + c * 32;
    LOADKV(kb + 32, kfB, vfB);
    PROCESS(kb, kfA, vfA, vt0);
    if (c + 2 < nch) LOADKV(kb + 64, kfA, vfA);
    PROCESS(kb + 32, kfB, vfB, vt1);
  }
  if (c < nch) PROCESS(kb0 + c * 32, kfA, vfA, vt0);

#undef LOADKV
#undef PROCESS

  lsum += __shfl_xor(lsum, 32, 64);
  const float inv = 1.f / lsum;
  unsigned short* aop = AO + (size_t)(qw0 + q) * DM + hD;
#pragma unroll
  for (int t2 = 0; t2 < 4; ++t2) {
    __hip_bfloat162 s0 = __float22bfloat162_rn(make_float2(o0[4*t2] * inv, o0[4*t2+1] * inv));
    __hip_bfloat162 s1 = __float22bfloat162_rn(make_float2(o0[4*t2+2] * inv, o0[4*t2+3] * inv));
    uint2 st; st.x = *(unsigned int*)&s0; st.y = *(unsigned int*)&s1;
    *(uint2*)(aop + 8 * t2 + 4 * hi) = st;
    __hip_bfloat162 s2 = __float22bfloat162_rn(make_float2(o1[4*t2] * inv, o1[4*t2+1] * inv));
    __hip_bfloat162 s3 = __float22bfloat162_rn(make_float2(o1[4*t2+2] * inv, o1[4*t2+3] * inv));
    uint2 st2; st2.x = *(unsigned int*)&s2; st2.y = *(unsigned int*)&s3;
    *(uint2*)(aop + 32 + 8 * t2 + 4 * hi) = st2;
  }
}

// ---------------------------------------------------------------------------
extern "C" void kernel_launch(void* const* d_in, const int* in_sizes, int n_in,
                              void* d_out, int out_size, void* d_ws, size_t ws_size,
                              hipStream_t stream) {
  const float* x  = (const float*)d_in[0];
  const float* qw = (const float*)d_in[1];
  const float* qb = (const float*)d_in[2];
  const float* kw = (const float*)d_in[3];
  const float* kb = (const float*)d_in[4];
  const float* vw = (const float*)d_in[5];
  const float* vb = (const float*)d_in[6];
  const float* ow = (const float*)d_in[7];
  const float* ob = (const float*)d_in[8];

  const size_t SD = (size_t)S_LEN * DM;
  unsigned short* Qb  = (unsigned short*)d_ws;
  unsigned short* Kb  = Qb + SD;
  unsigned short* Vb  = Kb + SD;
  unsigned short* AOb = Vb + SD;
  unsigned short* Xb  = AOb + SD;
  unsigned short* Wcv = Xb + SD;

  cvt_all<<<dim3(2048, 5), 256, 0, stream>>>(x, qw, kw, vw, ow, Xb, Wcv);
  gemm_qkv_fused<<<dim3(16, 16), 512, 0, stream>>>(Xb, Wcv, qb, kb, vb, Qb);
  attn<<<dim3(S_LEN / 128, NH), 256, 0, stream>>>(Qb, Kb, Vb, AOb);
  gemm_out<<<dim3(32, 8), 256, 0, stream>>>(AOb, Wcv + (size_t)3 * DM * DM, ob, (float*)d_out);
}